// Round 2
// baseline (337.332 us; speedup 1.0000x reference)
//
#include <hip/hip_runtime.h>
#include <hip/hip_bf16.h>

// Problem constants (match reference)
#define Bsz 32
#define Ssz 512
#define Dsz 768
#define Psz 256
#define Hsz 12
#define DHsz 64
#define DFFsz 3072
#define EPS_LN 1e-5f
#define EPS_TRIP 1e-6f

// ---------------- Pool kernel ----------------
// One block per pair: cls row + s/p/n ragged mean-pools.
// mem[(2p+0)] = cls, mem[(2p+1)] = s_emb, qin[p] = p_emb, qin[P+p] = n_emb.
__global__ __launch_bounds__(256) void pool_kernel(
    const float* __restrict__ sent, const int* __restrict__ sidx,
    const int* __restrict__ s_span, const int* __restrict__ p_span,
    const int* __restrict__ n_span,
    float* __restrict__ mem, float* __restrict__ qin)
{
    int p = blockIdx.x;
    int b = sidx[p];
    const float* base = sent + (size_t)b * Ssz * Dsz;
    int ss = s_span[2*p], se = s_span[2*p+1];
    int ps = p_span[2*p], pe = p_span[2*p+1];
    int ns = n_span[2*p], ne = n_span[2*p+1];
    float is  = 1.0f / (float)(se - ss);
    float ip  = 1.0f / (float)(pe - ps);
    float in_ = 1.0f / (float)(ne - ns);
    for (int d = threadIdx.x; d < Dsz; d += 256) {
        float cls = base[d];
        float as = 0.f, ap = 0.f, an = 0.f;
        for (int s = ss; s < se; ++s) as += base[(size_t)s*Dsz + d];
        for (int s = ps; s < pe; ++s) ap += base[(size_t)s*Dsz + d];
        for (int s = ns; s < ne; ++s) an += base[(size_t)s*Dsz + d];
        as *= is; ap *= ip; an *= in_;
        mem[(size_t)(2*p+0)*Dsz + d] = cls;
        mem[(size_t)(2*p+1)*Dsz + d] = as;
        qin[(size_t)(0*Psz + p)*Dsz + d] = ap;
        qin[(size_t)(1*Psz + p)*Dsz + d] = an;
    }
}

// ---------------- Generic fp32 GEMM core ----------------
// C[M,N](ldN) = A[M,Kloop](lda) @ W[Kloop,N](ldN) (+bias) (opt relu)
// Block tile 64x64, 256 threads, 4x4 per thread, BK=16.
#define BM 64
#define BN 64
#define BKs 16

__device__ __forceinline__ void gemm_core(
    const float* __restrict__ A, int lda,
    const float* __restrict__ W,
    const float* __restrict__ bias, float* __restrict__ C,
    int N, int Kloop, int relu, int bx, int by)
{
    __shared__ float As[BKs][BM];
    __shared__ float Bs[BKs][BN];
    int tid = threadIdx.x;
    int row0 = by * BM, col0 = bx * BN;
    int tx = tid & 15, ty = tid >> 4;
    int am = tid >> 2, ak = (tid & 3) * 4;    // A loader: row am, 4 k's
    int bk_ = tid >> 4, bn_ = (tid & 15) * 4; // B loader: k bk_, 4 n's
    const float* Aptr = A + (size_t)(row0 + am) * lda + ak;
    const float* Wptr = W + (size_t)bk_ * N + col0 + bn_;

    float acc[4][4];
    #pragma unroll
    for (int i = 0; i < 4; ++i)
        #pragma unroll
        for (int j = 0; j < 4; ++j) acc[i][j] = 0.f;

    for (int k0 = 0; k0 < Kloop; k0 += BKs) {
        float4 av = *(const float4*)(Aptr + k0);
        float4 wv = *(const float4*)(Wptr + (size_t)k0 * N);
        __syncthreads();
        As[ak+0][am] = av.x;
        As[ak+1][am] = av.y;
        As[ak+2][am] = av.z;
        As[ak+3][am] = av.w;
        *(float4*)&Bs[bk_][bn_] = wv;
        __syncthreads();
        #pragma unroll
        for (int kk = 0; kk < BKs; ++kk) {
            float4 a = *(const float4*)&As[kk][ty*4];
            float4 b = *(const float4*)&Bs[kk][tx*4];
            acc[0][0] += a.x*b.x; acc[0][1] += a.x*b.y; acc[0][2] += a.x*b.z; acc[0][3] += a.x*b.w;
            acc[1][0] += a.y*b.x; acc[1][1] += a.y*b.y; acc[1][2] += a.y*b.z; acc[1][3] += a.y*b.w;
            acc[2][0] += a.z*b.x; acc[2][1] += a.z*b.y; acc[2][2] += a.z*b.z; acc[2][3] += a.z*b.w;
            acc[3][0] += a.w*b.x; acc[3][1] += a.w*b.y; acc[3][2] += a.w*b.z; acc[3][3] += a.w*b.w;
        }
    }
    float bx_ = 0.f, by_ = 0.f, bz_ = 0.f, bw_ = 0.f;
    if (bias) {
        float4 bv4 = *(const float4*)(bias + col0 + tx*4);
        bx_ = bv4.x; by_ = bv4.y; bz_ = bv4.z; bw_ = bv4.w;
    }
    #pragma unroll
    for (int i = 0; i < 4; ++i) {
        float4 res;
        res.x = acc[i][0] + bx_;
        res.y = acc[i][1] + by_;
        res.z = acc[i][2] + bz_;
        res.w = acc[i][3] + bw_;
        if (relu) {
            res.x = fmaxf(res.x, 0.f); res.y = fmaxf(res.y, 0.f);
            res.z = fmaxf(res.z, 0.f); res.w = fmaxf(res.w, 0.f);
        }
        *(float4*)(C + (size_t)(row0 + ty*4 + i) * N + col0 + tx*4) = res;
    }
}

// Plain GEMM (full K)
__global__ __launch_bounds__(256) void gemm_kernel(
    const float* __restrict__ A, const float* __restrict__ W,
    const float* __restrict__ bias, float* __restrict__ C,
    int N, int K, int relu)
{
    gemm_core(A, K, W, bias, C, N, K, relu, blockIdx.x, blockIdx.y);
}

// Split-K GEMM: blockIdx.z = k-slice; partial written to Cpart + z*pstride.
// Bias added only in slice 0; consumer (LN) sums the slices.
__global__ __launch_bounds__(256) void gemm_splitk_kernel(
    const float* __restrict__ A, const float* __restrict__ W,
    const float* __restrict__ bias, float* __restrict__ Cpart,
    int N, int Ktot, int Ks, size_t pstride)
{
    int ks = blockIdx.z;
    gemm_core(A + (size_t)ks * Ks, Ktot,
              W + (size_t)ks * Ks * N,
              (ks == 0) ? bias : nullptr,
              Cpart + (size_t)ks * pstride,
              N, Ks, 0, blockIdx.x, blockIdx.y);
}

// Fused 3-way projection: z=0 -> kh = mem@Wk+bk, z=1 -> vh = mem@Wv+bv,
// z=2 -> qh = qin@Wq+bq. All [512,768]@[768,768].
struct ProjArgs {
    const float* A[3];
    const float* W[3];
    const float* bias[3];
    float* C[3];
};

__global__ __launch_bounds__(256) void proj3_kernel(ProjArgs pa)
{
    int j = blockIdx.z;
    gemm_core(pa.A[j], Dsz, pa.W[j], pa.bias[j], pa.C[j], Dsz, Dsz, 0,
              blockIdx.x, blockIdx.y);
}

// ---------------- Attention (2-slot, per head softmax) ----------------
// grid: 512 blocks (branch*256 + pair), 64 threads (one wave).
__global__ __launch_bounds__(64) void attn_kernel(
    const float* __restrict__ qh, const float* __restrict__ kh,
    const float* __restrict__ vh, float* __restrict__ obuf)
{
    int r = blockIdx.x;       // 0..511 ; row in q layout
    int p = r & (Psz - 1);
    int lane = threadIdx.x;
    const float* q  = qh + (size_t)r * Dsz;
    const float* k0 = kh + (size_t)(2*p) * Dsz;
    const float* k1 = k0 + Dsz;
    const float* v0 = vh + (size_t)(2*p) * Dsz;
    const float* v1 = v0 + Dsz;
    float* o = obuf + (size_t)r * Dsz;
    #pragma unroll
    for (int h = 0; h < Hsz; ++h) {
        int idx = h * DHsz + lane;
        float qv = q[idx];
        float s0 = qv * k0[idx];
        float s1 = qv * k1[idx];
        #pragma unroll
        for (int off = 32; off; off >>= 1) {
            s0 += __shfl_xor(s0, off);
            s1 += __shfl_xor(s1, off);
        }
        s0 *= 0.125f;  // 1/sqrt(64)
        s1 *= 0.125f;
        float m = fmaxf(s0, s1);
        float e0 = expf(s0 - m), e1 = expf(s1 - m);
        float inv = 1.f / (e0 + e1);
        o[idx] = (e0 * inv) * v0[idx] + (e1 * inv) * v1[idx];
    }
}

// ---------------- Residual + (multi-partial) + LayerNorm ----------------
// out[r] = LN(x[r] + sum_{q<nparts} y[q*pstride + r*D + :]) * g + b
__global__ __launch_bounds__(256) void ln_kernel(
    const float* __restrict__ x, const float* __restrict__ y,
    int nparts, size_t pstride,
    const float* __restrict__ g, const float* __restrict__ b,
    float* __restrict__ out)
{
    __shared__ float sb[4];
    int r = blockIdx.x;
    int t = threadIdx.x;
    float v[3];
    float s = 0.f;
    #pragma unroll
    for (int i = 0; i < 3; ++i) {
        int d = t + i * 256;
        float acc = x[(size_t)r*Dsz + d];
        for (int q = 0; q < nparts; ++q)
            acc += y[(size_t)q*pstride + (size_t)r*Dsz + d];
        v[i] = acc;
        s += acc;
    }
    #pragma unroll
    for (int off = 32; off; off >>= 1) s += __shfl_xor(s, off);
    if ((t & 63) == 0) sb[t >> 6] = s;
    __syncthreads();
    float mean = (sb[0] + sb[1] + sb[2] + sb[3]) * (1.0f / Dsz);
    __syncthreads();
    float sv = 0.f;
    #pragma unroll
    for (int i = 0; i < 3; ++i) { float d0 = v[i] - mean; sv += d0 * d0; }
    #pragma unroll
    for (int off = 32; off; off >>= 1) sv += __shfl_xor(sv, off);
    if ((t & 63) == 0) sb[t >> 6] = sv;
    __syncthreads();
    float var = (sb[0] + sb[1] + sb[2] + sb[3]) * (1.0f / Dsz);
    float rstd = 1.0f / sqrtf(var + EPS_LN);
    #pragma unroll
    for (int i = 0; i < 3; ++i) {
        int d = t + i * 256;
        out[(size_t)r*Dsz + d] = (v[i] - mean) * rstd * g[d] + b[d];
    }
}

// ---------------- Triplet hinge loss ----------------
__global__ __launch_bounds__(256) void loss_kernel(
    const float* __restrict__ mem, const float* __restrict__ outb,
    float* __restrict__ d_out)
{
    __shared__ float sb0[4], sb1[4];
    int p = blockIdx.x;
    int t = threadIdx.x;
    const float* se = mem  + (size_t)(2*p+1) * Dsz;
    const float* ap = outb + (size_t)p * Dsz;
    const float* an = outb + (size_t)(Psz + p) * Dsz;
    float dp = 0.f, dn = 0.f;
    #pragma unroll
    for (int i = 0; i < 3; ++i) {
        int d = t + i * 256;
        float a = se[d] - ap[d] + EPS_TRIP; dp += a * a;
        float c = se[d] - an[d] + EPS_TRIP; dn += c * c;
    }
    #pragma unroll
    for (int off = 32; off; off >>= 1) {
        dp += __shfl_xor(dp, off);
        dn += __shfl_xor(dn, off);
    }
    if ((t & 63) == 0) { sb0[t >> 6] = dp; sb1[t >> 6] = dn; }
    __syncthreads();
    if (t == 0) {
        float dps = sqrtf(sb0[0] + sb0[1] + sb0[2] + sb0[3]);
        float dns = sqrtf(sb1[0] + sb1[1] + sb1[2] + sb1[3]);
        float loss = fmaxf(dps - dns + 1.0f, 0.f);
        atomicAdd(d_out, loss * (1.0f / Psz));
    }
}

// ---------------- Launch ----------------
extern "C" void kernel_launch(void* const* d_in, const int* in_sizes, int n_in,
                              void* d_out, int out_size, void* d_ws, size_t ws_size,
                              hipStream_t stream) {
    const float* sent  = (const float*)d_in[0];
    const int*   sidx  = (const int*)d_in[1];
    const int*   sspan = (const int*)d_in[2];
    const int*   pspan = (const int*)d_in[3];
    const int*   nspan = (const int*)d_in[4];
    const float* Wq = (const float*)d_in[5];
    const float* bq = (const float*)d_in[6];
    const float* Wk = (const float*)d_in[7];
    const float* bk = (const float*)d_in[8];
    const float* Wv = (const float*)d_in[9];
    const float* bv = (const float*)d_in[10];
    const float* Wo = (const float*)d_in[11];
    const float* bo = (const float*)d_in[12];
    const float* ln1g = (const float*)d_in[13];
    const float* ln1b = (const float*)d_in[14];
    const float* ln2g = (const float*)d_in[15];
    const float* ln2b = (const float*)d_in[16];
    const float* W1 = (const float*)d_in[17];
    const float* b1 = (const float*)d_in[18];
    const float* W2 = (const float*)d_in[19];
    const float* b2 = (const float*)d_in[20];
    float* out = (float*)d_out;

    // Workspace layout (floats); F = 512*768 = 1.5 MB
    // ws0 mem | ws1 qin | ws2..5 {kh,vh,qh,(spare)} -> reused as 4 split-K
    // partials for Wo and later FFN2 | ws6 obuf -> outb | ws7 hbuf |
    // ws8..11 f1 [512,3072].  Total 12F = 18.9 MB.
    const size_t F = (size_t)512 * Dsz;
    float* ws    = (float*)d_ws;
    float* mem   = ws + 0 * F;
    float* qin   = ws + 1 * F;
    float* kh    = ws + 2 * F;
    float* vh    = ws + 3 * F;
    float* qh    = ws + 4 * F;
    float* partb = ws + 2 * F;   // 4 partial buffers, stride F (kh,vh,qh dead when used)
    float* obuf  = ws + 6 * F;
    float* hbuf  = ws + 7 * F;
    float* f1    = ws + 8 * F;   // 4F
    float* outb  = ws + 6 * F;   // reuse obuf after Wo GEMM

    hipMemsetAsync(d_out, 0, sizeof(float), stream);

    // 1. pooling (256 blocks)
    pool_kernel<<<Psz, 256, 0, stream>>>(sent, sidx, sspan, pspan, nspan, mem, qin);

    // 2. K/V/Q projections fused (12x8x3 = 288 blocks)
    ProjArgs pa;
    pa.A[0] = mem;  pa.W[0] = Wk; pa.bias[0] = bk; pa.C[0] = kh;
    pa.A[1] = mem;  pa.W[1] = Wv; pa.bias[1] = bv; pa.C[1] = vh;
    pa.A[2] = qin;  pa.W[2] = Wq; pa.bias[2] = bq; pa.C[2] = qh;
    proj3_kernel<<<dim3(Dsz/BN, 512/BM, 3), 256, 0, stream>>>(pa);

    // 3. attention (512 one-wave blocks)
    attn_kernel<<<512, 64, 0, stream>>>(qh, kh, vh, obuf);

    // 4. output projection, split-K=4 (12x8x4 = 384 blocks), partials ws2..5
    gemm_splitk_kernel<<<dim3(Dsz/BN, 512/BM, 4), 256, 0, stream>>>(
        obuf, Wo, bo, partb, Dsz, Dsz, Dsz/4, F);

    // 5. h = LN1(x + sum partials)  (512 blocks)
    ln_kernel<<<512, 256, 0, stream>>>(qin, partb, 4, F, ln1g, ln1b, hbuf);

    // 6. f1 = relu(h @ W1 + b1)  (48x8 = 384 blocks)
    gemm_kernel<<<dim3(DFFsz/BN, 512/BM), 256, 0, stream>>>(hbuf, W1, b1, f1, DFFsz, Dsz, 1);

    // 7. f2 partials = f1 @ W2 + b2, split-K=4 (12x8x4 = 384 blocks)
    gemm_splitk_kernel<<<dim3(Dsz/BN, 512/BM, 4), 256, 0, stream>>>(
        f1, W2, b2, partb, Dsz, DFFsz, DFFsz/4, F);

    // 8. out = LN2(h + sum partials)  (512 blocks)
    ln_kernel<<<512, 256, 0, stream>>>(hbuf, partb, 4, F, ln2g, ln2b, outb);

    // 9. triplet hinge loss (mean over pairs)
    loss_kernel<<<Psz, 256, 0, stream>>>(mem, outb, out);
}

// Round 6
// 265.802 us; speedup vs baseline: 1.2691x; 1.2691x over previous
//
#include <hip/hip_runtime.h>
#include <hip/hip_bf16.h>

// Problem constants
#define Dsz 768
#define Psz 256
#define Hsz 12
#define DHsz 64
#define DFFsz 3072
#define Msz 512           // rows of all activation matrices (2*P)
#define EPS_LN 1e-5f
#define EPS_TRIP 1e-6f

typedef unsigned short u16;
typedef __attribute__((ext_vector_type(8))) short bf16x8;
typedef __attribute__((ext_vector_type(4))) float f32x4;

__device__ __forceinline__ u16 f2bf(float f) {
    __hip_bfloat16 h = __float2bfloat16(f);
    u16 u; __builtin_memcpy(&u, &h, 2); return u;
}

// ---------------- Pool kernel ----------------
// mem[(2p+0)]=cls, mem[(2p+1)]=s_emb (f32, for loss); bf16 copies memb;
// qin[p]=p_emb, qin[P+p]=n_emb (f32 residual) + bf16 qinb (GEMM A).
__global__ __launch_bounds__(256) void pool_kernel(
    const float* __restrict__ sent, const int* __restrict__ sidx,
    const int* __restrict__ s_span, const int* __restrict__ p_span,
    const int* __restrict__ n_span,
    float* __restrict__ mem, float* __restrict__ qin,
    u16* __restrict__ memb, u16* __restrict__ qinb)
{
    int p = blockIdx.x;
    int b = sidx[p];
    const float* base = sent + (size_t)b * 512 * Dsz;
    int ss = s_span[2*p], se = s_span[2*p+1];
    int ps = p_span[2*p], pe = p_span[2*p+1];
    int ns = n_span[2*p], ne = n_span[2*p+1];
    float is  = 1.0f / (float)(se - ss);
    float ip  = 1.0f / (float)(pe - ps);
    float in_ = 1.0f / (float)(ne - ns);
    for (int d = threadIdx.x; d < Dsz; d += 256) {
        float cls = base[d];
        float as = 0.f, ap = 0.f, an = 0.f;
        for (int s = ss; s < se; ++s) as += base[(size_t)s*Dsz + d];
        for (int s = ps; s < pe; ++s) ap += base[(size_t)s*Dsz + d];
        for (int s = ns; s < ne; ++s) an += base[(size_t)s*Dsz + d];
        as *= is; ap *= ip; an *= in_;
        mem[(size_t)(2*p+0)*Dsz + d] = cls;
        mem[(size_t)(2*p+1)*Dsz + d] = as;
        qin[(size_t)(0*Psz + p)*Dsz + d] = ap;
        qin[(size_t)(1*Psz + p)*Dsz + d] = an;
        memb[(size_t)(2*p+0)*Dsz + d] = f2bf(cls);
        memb[(size_t)(2*p+1)*Dsz + d] = f2bf(as);
        qinb[(size_t)(0*Psz + p)*Dsz + d] = f2bf(ap);
        qinb[(size_t)(1*Psz + p)*Dsz + d] = f2bf(an);
    }
}

// ---------------- Weight convert + transpose ----------------
// W[K,N] f32 -> WT[N,K] bf16, 64x64 tiles through LDS.
struct CvtArgs {
    const float* src[6];
    u16* dst[6];
    int K[6], N[6];
    int t0[7];    // cumulative tile offsets
};

__global__ __launch_bounds__(256) void cvt_kernel(CvtArgs ca)
{
    __shared__ float tile[64][65];
    int bid = blockIdx.x;
    int w = 0;
    while (bid >= ca.t0[w+1]) ++w;
    int local = bid - ca.t0[w];
    int K = ca.K[w], N = ca.N[w];
    int ntN = N >> 6;
    int tk = local / ntN, tn = local - tk * ntN;
    int k0 = tk << 6, n0 = tn << 6;
    const float* src = ca.src[w];
    u16* dst = ca.dst[w];
    int t = threadIdx.x;
    int r = t >> 2, q = t & 3;
    #pragma unroll
    for (int j = 0; j < 4; ++j) {
        int c4 = q + j*4;   // float4 index within row, 0..15
        float4 v = *(const float4*)(src + (size_t)(k0 + r)*N + n0 + c4*4);
        tile[r][c4*4+0] = v.x; tile[r][c4*4+1] = v.y;
        tile[r][c4*4+2] = v.z; tile[r][c4*4+3] = v.w;
    }
    __syncthreads();
    #pragma unroll
    for (int j = 0; j < 4; ++j) {
        int kc4 = q + j*4;
        ushort4 o;
        o.x = f2bf(tile[kc4*4+0][r]);
        o.y = f2bf(tile[kc4*4+1][r]);
        o.z = f2bf(tile[kc4*4+2][r]);
        o.w = f2bf(tile[kc4*4+3][r]);
        *(ushort4*)(dst + (size_t)(n0 + r)*K + k0 + kc4*4) = o;
    }
}

// ---------------- MFMA bf16 GEMM core ----------------
// C[M,N] = A[M,K]bf16 @ W  with W pre-transposed as WT[N,K]bf16.
// Block: 256 thr = 4 waves (2x2), wave tile 32x32 (2x2 fragments 16x16),
// block tile 64x64. Direct-global fragment loads (16B/lane), no LDS.
// Fragment layouts (m89-verified family):
//   a: A[row0 + (l&15)][k + (l>>4)*8 + e]
//   b: WT[col0 + (l&15)][k + (l>>4)*8 + e]
//   d: C[row0 + (l>>4)*4 + e][col0 + (l&15)]
__device__ __forceinline__ void mfma_gemm_core(
    const u16* __restrict__ A, int lda,
    const u16* __restrict__ WT, int ldw,
    const float* __restrict__ bias,
    float* __restrict__ Cf, u16* __restrict__ Cb, int ldc,
    int Kloop, int relu, int bx, int by)
{
    int tid = threadIdx.x;
    int lane = tid & 63, wave = tid >> 6;
    int wr = wave >> 1, wc = wave & 1;
    int row0 = by*64 + wr*32, col0 = bx*64 + wc*32;
    int r = lane & 15, kg = lane >> 4;
    const u16* Ap0 = A  + (size_t)(row0 + r)      * lda + kg*8;
    const u16* Ap1 = A  + (size_t)(row0 + 16 + r) * lda + kg*8;
    const u16* Bp0 = WT + (size_t)(col0 + r)      * ldw + kg*8;
    const u16* Bp1 = WT + (size_t)(col0 + 16 + r) * ldw + kg*8;
    f32x4 acc00 = {0.f,0.f,0.f,0.f}, acc01 = {0.f,0.f,0.f,0.f};
    f32x4 acc10 = {0.f,0.f,0.f,0.f}, acc11 = {0.f,0.f,0.f,0.f};
    for (int k = 0; k < Kloop; k += 64) {   // 2 K-steps of 32 per iter
        bf16x8 a0 = *(const bf16x8*)(Ap0 + k);
        bf16x8 a1 = *(const bf16x8*)(Ap1 + k);
        bf16x8 b0 = *(const bf16x8*)(Bp0 + k);
        bf16x8 b1 = *(const bf16x8*)(Bp1 + k);
        bf16x8 a2 = *(const bf16x8*)(Ap0 + k + 32);
        bf16x8 a3 = *(const bf16x8*)(Ap1 + k + 32);
        bf16x8 b2 = *(const bf16x8*)(Bp0 + k + 32);
        bf16x8 b3 = *(const bf16x8*)(Bp1 + k + 32);
        acc00 = __builtin_amdgcn_mfma_f32_16x16x32_bf16(a0, b0, acc00, 0, 0, 0);
        acc01 = __builtin_amdgcn_mfma_f32_16x16x32_bf16(a0, b1, acc01, 0, 0, 0);
        acc10 = __builtin_amdgcn_mfma_f32_16x16x32_bf16(a1, b0, acc10, 0, 0, 0);
        acc11 = __builtin_amdgcn_mfma_f32_16x16x32_bf16(a1, b1, acc11, 0, 0, 0);
        acc00 = __builtin_amdgcn_mfma_f32_16x16x32_bf16(a2, b2, acc00, 0, 0, 0);
        acc01 = __builtin_amdgcn_mfma_f32_16x16x32_bf16(a2, b3, acc01, 0, 0, 0);
        acc10 = __builtin_amdgcn_mfma_f32_16x16x32_bf16(a3, b2, acc10, 0, 0, 0);
        acc11 = __builtin_amdgcn_mfma_f32_16x16x32_bf16(a3, b3, acc11, 0, 0, 0);
    }
    float b0s = bias ? bias[col0 + r]      : 0.f;
    float b1s = bias ? bias[col0 + 16 + r] : 0.f;
    #pragma unroll
    for (int e = 0; e < 4; ++e) {
        int rr0 = row0 + kg*4 + e;
        int rr1 = rr0 + 16;
        float v00 = acc00[e] + b0s, v01 = acc01[e] + b1s;
        float v10 = acc10[e] + b0s, v11 = acc11[e] + b1s;
        if (relu) {
            v00 = fmaxf(v00, 0.f); v01 = fmaxf(v01, 0.f);
            v10 = fmaxf(v10, 0.f); v11 = fmaxf(v11, 0.f);
        }
        if (Cf) {
            Cf[(size_t)rr0*ldc + col0 + r]      = v00;
            Cf[(size_t)rr0*ldc + col0 + 16 + r] = v01;
            Cf[(size_t)rr1*ldc + col0 + r]      = v10;
            Cf[(size_t)rr1*ldc + col0 + 16 + r] = v11;
        }
        if (Cb) {
            Cb[(size_t)rr0*ldc + col0 + r]      = f2bf(v00);
            Cb[(size_t)rr0*ldc + col0 + 16 + r] = f2bf(v01);
            Cb[(size_t)rr1*ldc + col0 + r]      = f2bf(v10);
            Cb[(size_t)rr1*ldc + col0 + 16 + r] = f2bf(v11);
        }
    }
}

// Fused QKV projections (z selects)
struct Proj3Args {
    const u16* A[3];
    const u16* WT[3];
    const float* bias[3];
    float* C[3];
};
__global__ __launch_bounds__(256) void proj3_mfma(Proj3Args pa)
{
    int j = blockIdx.z;
    mfma_gemm_core(pa.A[j], Dsz, pa.WT[j], Dsz, pa.bias[j],
                   pa.C[j], nullptr, Dsz, Dsz, 0, blockIdx.x, blockIdx.y);
}

// Full-K GEMM, optional relu, f32 and/or bf16 output
__global__ __launch_bounds__(256) void gemm_mfma(
    const u16* __restrict__ A, int lda, const u16* __restrict__ WT, int ldw,
    const float* __restrict__ bias, float* __restrict__ Cf, u16* __restrict__ Cb,
    int ldc, int Kloop, int relu)
{
    mfma_gemm_core(A, lda, WT, ldw, bias, Cf, Cb, ldc, Kloop, relu,
                   blockIdx.x, blockIdx.y);
}

// Split-K GEMM: z = k-slice, partials to Cpart + z*pstride (f32);
// bias only on slice 0; consumer LN sums slices.
__global__ __launch_bounds__(256) void gemm_mfma_splitk(
    const u16* __restrict__ A, int lda, const u16* __restrict__ WT, int ldw,
    const float* __restrict__ bias, float* __restrict__ Cpart,
    int ldc, int Ks, size_t pstride)
{
    int s = blockIdx.z;
    mfma_gemm_core(A + (size_t)s * Ks, lda, WT + (size_t)s * Ks, ldw,
                   (s == 0) ? bias : nullptr,
                   Cpart + (size_t)s * pstride, nullptr, ldc, Ks, 0,
                   blockIdx.x, blockIdx.y);
}

// ---------------- Attention (2-slot softmax per head) ----------------
__global__ __launch_bounds__(64) void attn_kernel(
    const float* __restrict__ qh, const float* __restrict__ kh,
    const float* __restrict__ vh, u16* __restrict__ ob)
{
    int rblk = blockIdx.x;           // 0..511
    int p = rblk & (Psz - 1);
    int lane = threadIdx.x;
    const float* q  = qh + (size_t)rblk * Dsz;
    const float* k0 = kh + (size_t)(2*p) * Dsz;
    const float* k1 = k0 + Dsz;
    const float* v0 = vh + (size_t)(2*p) * Dsz;
    const float* v1 = v0 + Dsz;
    u16* o = ob + (size_t)rblk * Dsz;
    #pragma unroll
    for (int h = 0; h < Hsz; ++h) {
        int idx = h * DHsz + lane;
        float qv = q[idx];
        float s0 = qv * k0[idx];
        float s1 = qv * k1[idx];
        #pragma unroll
        for (int off = 32; off; off >>= 1) {
            s0 += __shfl_xor(s0, off);
            s1 += __shfl_xor(s1, off);
        }
        s0 *= 0.125f;   // 1/sqrt(64)
        s1 *= 0.125f;
        float m = fmaxf(s0, s1);
        float e0 = expf(s0 - m), e1 = expf(s1 - m);
        float inv = 1.f / (e0 + e1);
        o[idx] = f2bf((e0 * inv) * v0[idx] + (e1 * inv) * v1[idx]);
    }
}

// ---------------- Residual + partial-sum + LayerNorm ----------------
// out = LN(x + sum_q y[q*pstride + ...]) * g + b ; optional bf16 copy
__global__ __launch_bounds__(256) void ln_kernel(
    const float* __restrict__ x, const float* __restrict__ y,
    int nparts, size_t pstride,
    const float* __restrict__ g, const float* __restrict__ b,
    float* __restrict__ out, u16* __restrict__ out16)
{
    __shared__ float sb[4];
    int rr = blockIdx.x;
    int t = threadIdx.x;
    float v[3];
    float s = 0.f;
    #pragma unroll
    for (int i = 0; i < 3; ++i) {
        int d = t + i * 256;
        float acc = x[(size_t)rr*Dsz + d];
        for (int q = 0; q < nparts; ++q)
            acc += y[(size_t)q*pstride + (size_t)rr*Dsz + d];
        v[i] = acc;
        s += acc;
    }
    #pragma unroll
    for (int off = 32; off; off >>= 1) s += __shfl_xor(s, off);
    if ((t & 63) == 0) sb[t >> 6] = s;
    __syncthreads();
    float mean = (sb[0] + sb[1] + sb[2] + sb[3]) * (1.0f / Dsz);
    __syncthreads();
    float sv = 0.f;
    #pragma unroll
    for (int i = 0; i < 3; ++i) { float d0 = v[i] - mean; sv += d0 * d0; }
    #pragma unroll
    for (int off = 32; off; off >>= 1) sv += __shfl_xor(sv, off);
    if ((t & 63) == 0) sb[t >> 6] = sv;
    __syncthreads();
    float var = (sb[0] + sb[1] + sb[2] + sb[3]) * (1.0f / Dsz);
    float rstd = 1.0f / sqrtf(var + EPS_LN);
    #pragma unroll
    for (int i = 0; i < 3; ++i) {
        int d = t + i * 256;
        float o = (v[i] - mean) * rstd * g[d] + b[d];
        out[(size_t)rr*Dsz + d] = o;
        if (out16) out16[(size_t)rr*Dsz + d] = f2bf(o);
    }
}

// ---------------- Triplet hinge loss ----------------
__global__ __launch_bounds__(256) void loss_kernel(
    const float* __restrict__ mem, const float* __restrict__ outb,
    float* __restrict__ d_out)
{
    __shared__ float sb0[4], sb1[4];
    int p = blockIdx.x;
    int t = threadIdx.x;
    const float* se = mem  + (size_t)(2*p+1) * Dsz;
    const float* ap = outb + (size_t)p * Dsz;
    const float* an = outb + (size_t)(Psz + p) * Dsz;
    float dp = 0.f, dn = 0.f;
    #pragma unroll
    for (int i = 0; i < 3; ++i) {
        int d = t + i * 256;
        float a = se[d] - ap[d] + EPS_TRIP; dp += a * a;
        float c = se[d] - an[d] + EPS_TRIP; dn += c * c;
    }
    #pragma unroll
    for (int off = 32; off; off >>= 1) {
        dp += __shfl_xor(dp, off);
        dn += __shfl_xor(dn, off);
    }
    if ((t & 63) == 0) { sb0[t >> 6] = dp; sb1[t >> 6] = dn; }
    __syncthreads();
    if (t == 0) {
        float dps = sqrtf(sb0[0] + sb0[1] + sb0[2] + sb0[3]);
        float dns = sqrtf(sb1[0] + sb1[1] + sb1[2] + sb1[3]);
        float loss = fmaxf(dps - dns + 1.0f, 0.f);
        atomicAdd(d_out, loss * (1.0f / Psz));
    }
}

// ---------------- Launch ----------------
extern "C" void kernel_launch(void* const* d_in, const int* in_sizes, int n_in,
                              void* d_out, int out_size, void* d_ws, size_t ws_size,
                              hipStream_t stream) {
    const float* sent  = (const float*)d_in[0];
    const int*   sidx  = (const int*)d_in[1];
    const int*   sspan = (const int*)d_in[2];
    const int*   pspan = (const int*)d_in[3];
    const int*   nspan = (const int*)d_in[4];
    const float* Wq = (const float*)d_in[5];
    const float* bq = (const float*)d_in[6];
    const float* Wk = (const float*)d_in[7];
    const float* bk = (const float*)d_in[8];
    const float* Wv = (const float*)d_in[9];
    const float* bv = (const float*)d_in[10];
    const float* Wo = (const float*)d_in[11];
    const float* bo = (const float*)d_in[12];
    const float* ln1g = (const float*)d_in[13];
    const float* ln1b = (const float*)d_in[14];
    const float* ln2g = (const float*)d_in[15];
    const float* ln2b = (const float*)d_in[16];
    const float* W1 = (const float*)d_in[17];
    const float* b1 = (const float*)d_in[18];
    const float* W2 = (const float*)d_in[19];
    const float* b2 = (const float*)d_in[20];
    float* out = (float*)d_out;

    // Workspace layout in floats; F = 512*768 = 393216 (1.5 MB).
    // Lifetime overlaps: qh/kh/vh (steps 3-4) share partb (first write
    // step 5); outbf (written step 9) shares qin (dead after step 6).
    // Total 20F = 31.5 MB.
    const size_t F = (size_t)Msz * Dsz;
    float* ws   = (float*)d_ws;
    float* mem  = ws + 0*F;                    // f32 [512,768]  (loss input)
    float* qin  = ws + 1*F;                    // f32 residual
    float* outbf= ws + 1*F;                    // f32 LN2 out (overlap qin)
    float* hbuf = ws + 2*F;                    // f32 after LN1
    float* partb= ws + 3*F;                    // 4 split-K partials (4F)
    float* qh   = ws + 3*F;                    // overlap partb (dead by step 5)
    float* kh   = ws + 4*F;
    float* vh   = ws + 5*F;
    u16* memb   = (u16*)(ws + 7*F);            // bf16 [512,768]
    u16* qinb   = (u16*)(ws + 7*F) + F;        // bf16
    u16* obufb  = (u16*)(ws + 8*F);            // bf16 attention out
    u16* hbufb  = (u16*)(ws + 8*F) + F;        // bf16 LN1 out
    u16* f1b    = (u16*)(ws + 9*F);            // bf16 [512,3072] (2F floats)
    u16* WqT    = (u16*)(ws + 11*F);           // weights bf16 transposed, 9F
    u16* WkT    = WqT + (size_t)Dsz*Dsz;
    u16* WvT    = WkT + (size_t)Dsz*Dsz;
    u16* WoT    = WvT + (size_t)Dsz*Dsz;
    u16* W1T    = WoT + (size_t)Dsz*Dsz;       // [3072,768]
    u16* W2T    = W1T + (size_t)Dsz*DFFsz;     // [768,3072]

    hipMemsetAsync(d_out, 0, sizeof(float), stream);

    // 1. pooling (+bf16 copies)
    pool_kernel<<<Psz, 256, 0, stream>>>(sent, sidx, sspan, pspan, nspan,
                                         mem, qin, memb, qinb);

    // 2. weight convert + transpose (1728 tiles)
    CvtArgs ca;
    ca.src[0]=Wq; ca.src[1]=Wk; ca.src[2]=Wv; ca.src[3]=Wo; ca.src[4]=W1; ca.src[5]=W2;
    ca.dst[0]=WqT; ca.dst[1]=WkT; ca.dst[2]=WvT; ca.dst[3]=WoT; ca.dst[4]=W1T; ca.dst[5]=W2T;
    ca.K[0]=Dsz; ca.K[1]=Dsz; ca.K[2]=Dsz; ca.K[3]=Dsz; ca.K[4]=Dsz;  ca.K[5]=DFFsz;
    ca.N[0]=Dsz; ca.N[1]=Dsz; ca.N[2]=Dsz; ca.N[3]=Dsz; ca.N[4]=DFFsz; ca.N[5]=Dsz;
    int acc_t = 0;
    for (int i = 0; i < 6; ++i) {
        ca.t0[i] = acc_t;
        acc_t += (ca.K[i] >> 6) * (ca.N[i] >> 6);
    }
    ca.t0[6] = acc_t;   // 1728
    cvt_kernel<<<acc_t, 256, 0, stream>>>(ca);

    // 3. fused K/V/Q projections (12x8x3 blocks)
    Proj3Args pa;
    pa.A[0]=memb; pa.WT[0]=WkT; pa.bias[0]=bk; pa.C[0]=kh;
    pa.A[1]=memb; pa.WT[1]=WvT; pa.bias[1]=bv; pa.C[1]=vh;
    pa.A[2]=qinb; pa.WT[2]=WqT; pa.bias[2]=bq; pa.C[2]=qh;
    proj3_mfma<<<dim3(Dsz/64, Msz/64, 3), 256, 0, stream>>>(pa);

    // 4. attention -> bf16
    attn_kernel<<<Msz, 64, 0, stream>>>(qh, kh, vh, obufb);

    // 5. Wo projection split-K=4 (Ks=192)
    gemm_mfma_splitk<<<dim3(Dsz/64, Msz/64, 4), 256, 0, stream>>>(
        obufb, Dsz, WoT, Dsz, bo, partb, Dsz, Dsz/4, F);

    // 6. h = LN1(qin + sum partials), f32+bf16
    ln_kernel<<<Msz, 256, 0, stream>>>(qin, partb, 4, F, ln1g, ln1b, hbuf, hbufb);

    // 7. f1 = relu(h @ W1 + b1) -> bf16 only (48x8 blocks)
    gemm_mfma<<<dim3(DFFsz/64, Msz/64), 256, 0, stream>>>(
        hbufb, Dsz, W1T, Dsz, b1, nullptr, f1b, DFFsz, Dsz, 1);

    // 8. f2 partials = f1 @ W2 + b2, split-K=4 (Ks=768)
    gemm_mfma_splitk<<<dim3(Dsz/64, Msz/64, 4), 256, 0, stream>>>(
        f1b, DFFsz, W2T, DFFsz, b2, partb, Dsz, DFFsz/4, F);

    // 9. out = LN2(h + sum partials)
    ln_kernel<<<Msz, 256, 0, stream>>>(hbuf, partb, 4, F, ln2g, ln2b, outbf, nullptr);

    // 10. triplet hinge loss
    loss_kernel<<<Psz, 256, 0, stream>>>(mem, outbf, out);
}